// Round 7
// baseline (126.220 us; speedup 1.0000x reference)
//
#include <hip/hip_runtime.h>
#include <stdint.h>

#define NBL 8
#define MBS 512   // rows per blade
#define CIN 1024  // K per blade block
#define UQ  1024  // output cols per blade

// sigma[i][k]: j such that blade_i * blade_j = sign * blade_k ; sg[i][k] = sign
__device__ __constant__ int c_sigma[8][8] = {
  {0,1,2,3,4,5,6,7},
  {1,0,4,5,2,3,7,6},
  {2,4,0,6,1,7,3,5},
  {3,5,6,0,7,1,2,4},
  {4,2,1,7,0,6,5,3},
  {5,3,7,1,6,0,4,2},
  {6,7,3,2,5,4,0,1},
  {7,6,5,4,3,2,1,0},
};
__device__ __constant__ int c_sg[8][8] = {
  { 1, 1, 1, 1, 1, 1, 1, 1},
  { 1, 1, 1, 1, 1, 1, 1, 1},
  { 1,-1, 1, 1,-1,-1, 1,-1},
  { 1,-1,-1, 1, 1,-1,-1, 1},
  {-1, 1,-1,-1, 1, 1,-1, 1},
  {-1, 1, 1,-1,-1, 1, 1,-1},
  {-1,-1, 1,-1, 1,-1, 1, 1},
  {-1,-1, 1,-1, 1,-1, 1, 1},
};

typedef short bf16x8 __attribute__((ext_vector_type(8)));
typedef float f32x4 __attribute__((ext_vector_type(4)));

__device__ __forceinline__ uint32_t f2bf(float f) {
  uint32_t u = __float_as_uint(f);
  return (u + 0x7fffu + ((u >> 16) & 1u)) >> 16;  // RNE
}
__device__ __forceinline__ uint32_t pk2(float lo, float hi) {
  return f2bf(lo) | (f2bf(hi) << 16);
}

// ---------------- prepass: blocked workspace layouts ----------------
// X'[i][chunk c 0..127][row m 0..511][8 elems]  (+ and - sign copies)
// W'[j][chunk c 0..127][col u 0..1023][8 elems]
// chunk c covers k = c*8..c*8+7 within the blade's K=1024.

// x (4096x1024 f32) -> Xp'/Xn' blocked bf16. Block: 32 chunks x 32 rows.
__global__ void cvt_x_kernel(const float* __restrict__ x,
                             uint4* __restrict__ xp, uint4* __restrict__ xn) {
  __shared__ uint4 t16[32 * 33];  // [chunk 32][row 32], stride 33 (pad)
  const int tid = threadIdx.x;           // 256
  const int tx = tid & 31, ty = tid >> 5;
  const int i  = blockIdx.x >> 2;        // blade 0..7
  const int cb = blockIdx.x & 3;         // chunk-block 0..3 (32 chunks each)
  const int m0 = blockIdx.y * 32;        // row-block
#pragma unroll
  for (int r = 0; r < 4; ++r) {
    const int m = m0 + ty + r * 8;
    const float* src = x + ((size_t)(i * MBS + m)) * CIN + cb * 256 + tx * 8;
    float4 a = *(const float4*)src;
    float4 b = *(const float4*)(src + 4);
    uint4 p;
    p.x = pk2(a.x, a.y); p.y = pk2(a.z, a.w);
    p.z = pk2(b.x, b.y); p.w = pk2(b.z, b.w);
    t16[tx * 33 + ty + r * 8] = p;  // [chunk tx][row]
  }
  __syncthreads();
#pragma unroll
  for (int p = 0; p < 4; ++p) {
    const int slot = p * 256 + tid;      // 1024 slots
    const int cc = slot >> 5, mm = slot & 31;
    uint4 v = t16[cc * 33 + mm];
    const size_t o = (size_t)(i * 128 + cb * 32 + cc) * 512 + m0 + mm;
    xp[o] = v;
    uint4 n;
    n.x = v.x ^ 0x80008000u; n.y = v.y ^ 0x80008000u;
    n.z = v.z ^ 0x80008000u; n.w = v.w ^ 0x80008000u;
    xn[o] = n;
  }
}

// W [1024][8192] f32 -> W' blocked bf16 (transpose k<->u). Tile 64n x 32k.
__global__ void cvt_w_kernel(const float* __restrict__ w, uint4* __restrict__ wp) {
  __shared__ float tile[32][65];
  const int tid = threadIdx.x;  // 256
  const int tx = tid & 63, ty = tid >> 6;   // n within tile, k-round
  const int n0 = blockIdx.x * 64;   // over 8192 n
  const int k0 = blockIdx.y * 32;   // over 1024 k
#pragma unroll
  for (int r = 0; r < 8; ++r) {
    const int kr = ty * 8 + r;
    tile[kr][tx] = w[(size_t)(k0 + kr) * 8192 + n0 + tx];
  }
  __syncthreads();
  {
    const int cc = tid >> 6;   // local chunk 0..3
    const int uu = tid & 63;
    const int nn = n0 + uu;
    const int j = nn >> 10;
    const int col = nn & 1023;
    uint4 v;
    v.x = pk2(tile[cc * 8 + 0][uu], tile[cc * 8 + 1][uu]);
    v.y = pk2(tile[cc * 8 + 2][uu], tile[cc * 8 + 3][uu]);
    v.z = pk2(tile[cc * 8 + 4][uu], tile[cc * 8 + 5][uu]);
    v.w = pk2(tile[cc * 8 + 6][uu], tile[cc * 8 + 7][uu]);
    wp[(size_t)(j * 128 + blockIdx.y * 4 + cc) * 1024 + col] = v;
  }
}

// out[r][c] = bias[(r>>9)*1024 + c]  (prefill; GEMM atomically accumulates)
__global__ void bias_fill(const float* __restrict__ bias, float4* __restrict__ out) {
  int idx = blockIdx.x * 256 + threadIdx.x;
  int row = idx >> 8;
  int c4 = idx & 255;
  int k = row >> 9;
  out[idx] = ((const float4*)(bias + k * UQ))[c4];
}

#define BAR() do { asm volatile("s_barrier" ::: "memory");                    \
                   __builtin_amdgcn_sched_barrier(0); } while (0)
#define VMW(N) asm volatile("s_waitcnt vmcnt(" #N ")" ::: "memory")

// ---- 256x256x(BK=32) ring-4 GEMM, split-K=4, 8 waves (2x4) ----
// Wave tile 128x64 -> 42.7 MFMA-FLOP per LDS byte read (vs 32 at 64x64):
// per CU/step LDS ~96KB read + 32KB write (~1300 cyc) vs MFMA 1241 cyc.
// Ring-4 x 32KB = 128 KB dynamic LDS, 1 block/CU. Prefetch depth 3 steps,
// one vmcnt(8)+barrier per step (stage(t+1) provably landed; never drain 0).
// LDS tile layout [chunk 0..3][rows 0..255][8]: b128 reads hit the
// 8-touch/bank minimum, no XOR needed (measured 0 conflicts, rounds 3-6).
__global__ __launch_bounds__(512, 1) void ga_gemm256(
    const uint16_t* __restrict__ xp, const uint16_t* __restrict__ xn,
    const uint16_t* __restrict__ wp, float* __restrict__ out) {
  extern __shared__ uint16_t lds[];  // [4 ring][A 8192 | B 8192] u16 = 128 KB

  const int tid  = threadIdx.x;
  const int bid  = blockIdx.x;
  const int s    = bid >> 6;          // K-split 0..3 (2 i-blocks each)
  const int k    = (bid >> 3) & 7;    // blade
  const int mt   = (bid >> 2) & 1;    // m-tile (256 rows)
  const int ut   = bid & 3;           // n-tile (256 cols)
  const int lane = tid & 63;
  const int wid  = tid >> 6;          // 0..7
  const int wr   = wid >> 2;          // 0..1  (128-row slice)
  const int wc   = wid & 3;           // 0..3  (64-col slice)
  const int r15  = lane & 15, hi = lane >> 4;

  // hoisted uniform tables for this split's 2 i-blocks
  uint32_t sig_pack = 0, pos_pack = 0;
#pragma unroll
  for (int ib = 0; ib < 2; ++ib) {
    sig_pack |= (uint32_t)c_sigma[s * 2 + ib][k] << (4 * ib);
    pos_pack |= (uint32_t)(c_sg[s * 2 + ib][k] > 0) << ib;
  }

  f32x4 acc[8][4];
  const f32x4 z = {0.f, 0.f, 0.f, 0.f};
#pragma unroll
  for (int a = 0; a < 8; ++a)
#pragma unroll
    for (int b = 0; b < 4; ++b) acc[a][b] = z;

  // stage step t (4 chunks x 256 rows of A and of B): 2+2 loads per thread
  auto stage = [&](int t) {
    const int ib = t >> 5;                       // 0/1 within split
    const int c0 = (t & 31) << 2;                // chunk base
    const int i  = s * 2 + ib;
    const int j  = (sig_pack >> (4 * ib)) & 15;
    const uint16_t* xb = ((pos_pack >> ib) & 1) ? xp : xn;
    uint16_t* la = lds + (size_t)(t & 3) * 16384;
    uint16_t* lb = la + 8192;
#pragma unroll
    for (int r = 0; r < 2; ++r) {
      const int e  = r * 512 + tid;              // 0..1023
      const int cc = c0 + (e >> 8);
      const int rw = e & 255;
      __builtin_amdgcn_global_load_lds(
          (const __attribute__((address_space(1))) uint32_t*)
              (xb + ((size_t)(i * 128 + cc) * 512 + mt * 256 + rw) * 8),
          (__attribute__((address_space(3))) uint32_t*)(la + e * 8), 16, 0, 0);
      __builtin_amdgcn_global_load_lds(
          (const __attribute__((address_space(1))) uint32_t*)
              (wp + ((size_t)(j * 128 + cc) * 1024 + ut * 256 + rw) * 8),
          (__attribute__((address_space(3))) uint32_t*)(lb + e * 8), 16, 0, 0);
    }
  };

  stage(0); stage(1); stage(2);
  VMW(8);   // stage(0) landed; (1),(2) in flight
  BAR();

  for (int t = 0; t < 64; ++t) {
    const int nt = (t + 3 < 63) ? t + 3 : 63;    // clamped tail (dup = benign)
    stage(nt);
    const uint16_t* base = lds + (size_t)(t & 3) * 16384;
    bf16x8 af[8], bfr[4];
#pragma unroll
    for (int f = 0; f < 8; ++f)
      af[f] = *(const bf16x8*)(base + ((hi << 8) + wr * 128 + f * 16 + r15) * 8);
#pragma unroll
    for (int g = 0; g < 4; ++g)
      bfr[g] = *(const bf16x8*)(base + 8192 + ((hi << 8) + wc * 64 + g * 16 + r15) * 8);
    __builtin_amdgcn_s_setprio(1);
#pragma unroll
    for (int f = 0; f < 8; ++f)
#pragma unroll
      for (int g = 0; g < 4; ++g)
        acc[f][g] = __builtin_amdgcn_mfma_f32_16x16x32_bf16(
            af[f], bfr[g], acc[f][g], 0, 0, 0);
    __builtin_amdgcn_s_setprio(0);
    VMW(8);   // stage(t+1) landed by end of this step (issued at t-2)
    BAR();
  }

  // epilogue: atomic accumulate (D: col = lane&15, row = (lane>>4)*4 + r)
  const int row0 = k * MBS + mt * 256 + wr * 128;
  const int col0 = ut * 256 + wc * 64;
#pragma unroll
  for (int g = 0; g < 4; ++g) {
    const int col = col0 + g * 16 + r15;
#pragma unroll
    for (int f = 0; f < 8; ++f) {
      const int r0 = row0 + f * 16 + hi * 4;
#pragma unroll
      for (int r = 0; r < 4; ++r)
        unsafeAtomicAdd(&out[(size_t)(r0 + r) * UQ + col], acc[f][g][r]);
    }
  }
}

// Fallback (ws too small): correct fp32 path, slow.
__global__ void ga_naive(const float* __restrict__ x, const float* __restrict__ w,
                         const float* __restrict__ bias, float* __restrict__ out) {
  int col = blockIdx.x * 256 + threadIdx.x;
  int row = blockIdx.y;
  int k = row >> 9, m = row & 511;
  float acc = bias[k * UQ + col];
  for (int i = 0; i < 8; ++i) {
    int j = c_sigma[i][k];
    float s = (float)c_sg[i][k];
    const float* xr = x + (size_t)(i * MBS + m) * CIN;
    const float* wc = w + (size_t)j * UQ + col;
    float a = 0.f;
    for (int c = 0; c < CIN; ++c) a = fmaf(xr[c], wc[(size_t)c * (NBL * UQ)], a);
    acc = fmaf(s, a, acc);
  }
  out[(size_t)row * UQ + col] = acc;
}

extern "C" void kernel_launch(void* const* d_in, const int* in_sizes, int n_in,
                              void* d_out, int out_size, void* d_ws, size_t ws_size,
                              hipStream_t stream) {
  const float* x    = (const float*)d_in[0];   // 4096*1024
  const float* W    = (const float*)d_in[1];   // 1024*8192
  const float* bias = (const float*)d_in[2];   // 8192
  float* out = (float*)d_out;                  // 4096*1024

  const size_t need = 32u * 1024u * 1024u;     // Xp' 8MB, Xn' 8MB, W' 16MB
  if (ws_size < need) {
    ga_naive<<<dim3(4, 4096), dim3(256), 0, stream>>>(x, W, bias, out);
    return;
  }

  uint16_t* xp = (uint16_t*)d_ws;
  uint16_t* xn = xp + 4194304;
  uint16_t* wp = xn + 4194304;

  cvt_x_kernel<<<dim3(32, 16), dim3(256), 0, stream>>>(x, (uint4*)xp, (uint4*)xn);
  cvt_w_kernel<<<dim3(128, 32), dim3(256), 0, stream>>>(W, (uint4*)wp);
  bias_fill<<<dim3(4096), dim3(256), 0, stream>>>(bias, (float4*)out);
  ga_gemm256<<<dim3(256), dim3(512), 131072, stream>>>(xp, xn, wp, out);
}

// Round 8
// 125.022 us; speedup vs baseline: 1.0096x; 1.0096x over previous
//
#include <hip/hip_runtime.h>
#include <stdint.h>

#define NBL 8
#define MBS 512   // rows per blade
#define CIN 1024  // K per blade block
#define UQ  1024  // output cols per blade

// sigma[i][k]: j such that blade_i * blade_j = sign * blade_k ; sg[i][k] = sign
__device__ __constant__ int c_sigma[8][8] = {
  {0,1,2,3,4,5,6,7},
  {1,0,4,5,2,3,7,6},
  {2,4,0,6,1,7,3,5},
  {3,5,6,0,7,1,2,4},
  {4,2,1,7,0,6,5,3},
  {5,3,7,1,6,0,4,2},
  {6,7,3,2,5,4,0,1},
  {7,6,5,4,3,2,1,0},
};
__device__ __constant__ int c_sg[8][8] = {
  { 1, 1, 1, 1, 1, 1, 1, 1},
  { 1, 1, 1, 1, 1, 1, 1, 1},
  { 1,-1, 1, 1,-1,-1, 1,-1},
  { 1,-1,-1, 1, 1,-1,-1, 1},
  {-1, 1,-1,-1, 1, 1,-1, 1},
  {-1, 1, 1,-1,-1, 1, 1,-1},
  {-1,-1, 1,-1, 1,-1, 1, 1},
  {-1,-1, 1,-1, 1,-1, 1, 1},
};

typedef short bf16x8 __attribute__((ext_vector_type(8)));
typedef float f32x4 __attribute__((ext_vector_type(4)));

__device__ __forceinline__ uint32_t f2bf(float f) {
  uint32_t u = __float_as_uint(f);
  return (u + 0x7fffu + ((u >> 16) & 1u)) >> 16;  // RNE
}
__device__ __forceinline__ uint32_t pk2(float lo, float hi) {
  return f2bf(lo) | (f2bf(hi) << 16);
}

// ---------------- prepass: blocked workspace layouts ----------------
// X'[i][chunk c 0..127][row m 0..511][8 elems]  (+ and - sign copies)
// W'[j][chunk c 0..127][col u 0..1023][8 elems]
// chunk c covers k = c*8..c*8+7 within the blade's K=1024.

// x (4096x1024 f32) -> Xp'/Xn' blocked bf16. Block: 32 chunks x 32 rows.
__global__ void cvt_x_kernel(const float* __restrict__ x,
                             uint4* __restrict__ xp, uint4* __restrict__ xn) {
  __shared__ uint4 t16[32 * 33];  // [chunk 32][row 32], stride 33 (pad)
  const int tid = threadIdx.x;           // 256
  const int tx = tid & 31, ty = tid >> 5;
  const int i  = blockIdx.x >> 2;        // blade 0..7
  const int cb = blockIdx.x & 3;         // chunk-block 0..3 (32 chunks each)
  const int m0 = blockIdx.y * 32;        // row-block
#pragma unroll
  for (int r = 0; r < 4; ++r) {
    const int m = m0 + ty + r * 8;
    const float* src = x + ((size_t)(i * MBS + m)) * CIN + cb * 256 + tx * 8;
    float4 a = *(const float4*)src;
    float4 b = *(const float4*)(src + 4);
    uint4 p;
    p.x = pk2(a.x, a.y); p.y = pk2(a.z, a.w);
    p.z = pk2(b.x, b.y); p.w = pk2(b.z, b.w);
    t16[tx * 33 + ty + r * 8] = p;  // [chunk tx][row]
  }
  __syncthreads();
#pragma unroll
  for (int p = 0; p < 4; ++p) {
    const int slot = p * 256 + tid;      // 1024 slots
    const int cc = slot >> 5, mm = slot & 31;
    uint4 v = t16[cc * 33 + mm];
    const size_t o = (size_t)(i * 128 + cb * 32 + cc) * 512 + m0 + mm;
    xp[o] = v;
    uint4 n;
    n.x = v.x ^ 0x80008000u; n.y = v.y ^ 0x80008000u;
    n.z = v.z ^ 0x80008000u; n.w = v.w ^ 0x80008000u;
    xn[o] = n;
  }
}

// W [1024][8192] f32 -> W' blocked bf16 (transpose k<->u). Tile 64n x 32k.
__global__ void cvt_w_kernel(const float* __restrict__ w, uint4* __restrict__ wp) {
  __shared__ float tile[32][65];
  const int tid = threadIdx.x;  // 256
  const int tx = tid & 63, ty = tid >> 6;   // n within tile, k-round
  const int n0 = blockIdx.x * 64;   // over 8192 n
  const int k0 = blockIdx.y * 32;   // over 1024 k
#pragma unroll
  for (int r = 0; r < 8; ++r) {
    const int kr = ty * 8 + r;
    tile[kr][tx] = w[(size_t)(k0 + kr) * 8192 + n0 + tx];
  }
  __syncthreads();
  {
    const int cc = tid >> 6;   // local chunk 0..3
    const int uu = tid & 63;
    const int nn = n0 + uu;
    const int j = nn >> 10;
    const int col = nn & 1023;
    uint4 v;
    v.x = pk2(tile[cc * 8 + 0][uu], tile[cc * 8 + 1][uu]);
    v.y = pk2(tile[cc * 8 + 2][uu], tile[cc * 8 + 3][uu]);
    v.z = pk2(tile[cc * 8 + 4][uu], tile[cc * 8 + 5][uu]);
    v.w = pk2(tile[cc * 8 + 6][uu], tile[cc * 8 + 7][uu]);
    wp[(size_t)(j * 128 + blockIdx.y * 4 + cc) * 1024 + col] = v;
  }
}

// out[r][c] = bias[(r>>9)*1024 + c]  (prefill; GEMM atomically accumulates)
__global__ void bias_fill(const float* __restrict__ bias, float4* __restrict__ out) {
  int idx = blockIdx.x * 256 + threadIdx.x;
  int row = idx >> 8;
  int c4 = idx & 255;
  int k = row >> 9;
  out[idx] = ((const float4*)(bias + k * UQ))[c4];
}

#define BAR() do { asm volatile("s_barrier" ::: "memory");                    \
                   __builtin_amdgcn_sched_barrier(0); } while (0)
#define VMW(N) asm volatile("s_waitcnt vmcnt(" #N ")" ::: "memory")

// ---- 256x128x(BK=32) reg-A GEMM, split-K=4, 4 waves of 128x64 ----
// A-fragments: global->VGPR direct (L2/L3-resident blocked X'), double-
// buffered afA/afB (static names). B only staged in LDS: ring-4 x 8KB.
// Per step: LOAD_A(t+1) [8 b128] ; STAGE_B(t+3) [2 gload_lds] ; READ_B(t)
// [4 ds_read_b128] ; VMW(12) ; 32 MFMA ; BAR.  VMW(12) proves A(t) and
// Bst(t+1) landed (12 = Bst(t+2)2 + A(t+1)8 + Bst(t+3)2). Never drains 0.
// LDS traffic/CU: ~2MB read + 1MB write (~13us) << MFMA 28.8us.

#define LOAD_A(DST, G) {                                                      \
  const int g_ = (G);                                                         \
  const uint16_t* pa_ = ((g_ & 32) ? paI1 : paI0) + (size_t)(g_ & 31) * 16384;\
  _Pragma("unroll")                                                           \
  for (int f = 0; f < 8; ++f)                                                 \
    DST[f] = *(const bf16x8*)(pa_ +                                           \
        (size_t)(hi * 512 + mt * 256 + wr * 128 + f * 16 + r15) * 8);         \
}

#define STAGE_B(G) {                                                          \
  const int g_ = (G);                                                         \
  const uint16_t* pb_ = ((g_ & 32) ? pbI1 : pbI0) + (size_t)(g_ & 31) * 32768;\
  uint16_t* lb_ = ldsb[g_ & 3];                                               \
  _Pragma("unroll")                                                           \
  for (int r = 0; r < 2; ++r) {                                               \
    const int e = r * 256 + tid;                                              \
    __builtin_amdgcn_global_load_lds(                                         \
        (const __attribute__((address_space(1))) uint32_t*)                   \
            (pb_ + (size_t)((e >> 7) * 8192 + (ut * 128 + (e & 127)) * 8)),   \
        (__attribute__((address_space(3))) uint32_t*)(lb_ + e * 8), 16, 0, 0);\
  }                                                                           \
}

#define READ_B(DST, T) {                                                      \
  const uint16_t* lb_ = ldsb[(T) & 3];                                        \
  _Pragma("unroll")                                                           \
  for (int g2 = 0; g2 < 4; ++g2)                                              \
    DST[g2] = *(const bf16x8*)(lb_ +                                          \
        (size_t)(hi * 128 + wc * 64 + g2 * 16 + r15) * 8);                    \
}

#define MFMA32(AF, BF) {                                                      \
  __builtin_amdgcn_s_setprio(1);                                              \
  _Pragma("unroll")                                                           \
  for (int f = 0; f < 8; ++f)                                                 \
    _Pragma("unroll")                                                         \
    for (int g2 = 0; g2 < 4; ++g2)                                            \
      acc[f][g2] = __builtin_amdgcn_mfma_f32_16x16x32_bf16(                   \
          AF[f], BF[g2], acc[f][g2], 0, 0, 0);                                \
  __builtin_amdgcn_s_setprio(0);                                              \
}

__global__ __launch_bounds__(256, 2) void ga_rega(
    const uint16_t* __restrict__ xp, const uint16_t* __restrict__ xn,
    const uint16_t* __restrict__ wp, float* __restrict__ out) {
  __shared__ uint16_t ldsb[4][4096];  // B ring: [buf][chunk 4][col 128][8] = 32 KB

  const int tid  = threadIdx.x;
  const int bid  = blockIdx.x;
  const int s    = bid >> 7;          // K-split 0..3 (2 i-blocks each)
  const int k    = (bid >> 4) & 7;    // blade
  const int mt   = (bid >> 3) & 1;    // m-tile (256 rows)
  const int ut   = bid & 7;           // n-tile (128 cols)
  const int lane = tid & 63;
  const int wid  = tid >> 6;          // 0..3
  const int wr   = wid >> 1;          // 0..1 (128-row slice)
  const int wc   = wid & 1;           // 0..1 (64-col slice)
  const int r15  = lane & 15, hi = lane >> 4;

  const int i0 = s * 2, i1 = s * 2 + 1;
  const uint16_t* paI0 = (c_sg[i0][k] > 0 ? xp : xn) + (size_t)i0 * 524288;
  const uint16_t* paI1 = (c_sg[i1][k] > 0 ? xp : xn) + (size_t)i1 * 524288;
  const uint16_t* pbI0 = wp + (size_t)c_sigma[i0][k] * 1048576;
  const uint16_t* pbI1 = wp + (size_t)c_sigma[i1][k] * 1048576;

  f32x4 acc[8][4];
  const f32x4 z = {0.f, 0.f, 0.f, 0.f};
#pragma unroll
  for (int a = 0; a < 8; ++a)
#pragma unroll
    for (int b = 0; b < 4; ++b) acc[a][b] = z;

  bf16x8 afA[8], afB[8], bfr[4];

  // prologue: Bst(0),Bst(1), A(0), Bst(2); wait so Bst(0) landed (14->12)
  STAGE_B(0); STAGE_B(1);
  LOAD_A(afA, 0);
  STAGE_B(2);
  VMW(12);
  BAR();

  for (int t = 0; t < 64; t += 2) {
    // even step t: compute afA, prefetch into afB
    {
      const int a1 = (t + 1 < 63) ? t + 1 : 63;
      const int b3 = (t + 3 < 63) ? t + 3 : 63;
      LOAD_A(afB, a1);
      STAGE_B(b3);
      READ_B(bfr, t);
      VMW(12);
      MFMA32(afA, bfr);
      BAR();
    }
    // odd step t+1: compute afB, prefetch into afA
    {
      const int a2 = (t + 2 < 63) ? t + 2 : 63;
      const int b4 = (t + 4 < 63) ? t + 4 : 63;
      LOAD_A(afA, a2);
      STAGE_B(b4);
      READ_B(bfr, t + 1);
      VMW(12);
      MFMA32(afB, bfr);
      BAR();
    }
  }

  // epilogue: atomic accumulate (D: col = lane&15, row = (lane>>4)*4 + r)
  const int row0 = k * MBS + mt * 256 + wr * 128;
  const int col0 = ut * 128 + wc * 64;
#pragma unroll
  for (int g2 = 0; g2 < 4; ++g2) {
    const int col = col0 + g2 * 16 + r15;
#pragma unroll
    for (int f = 0; f < 8; ++f) {
      const int r0 = row0 + f * 16 + hi * 4;
#pragma unroll
      for (int r = 0; r < 4; ++r)
        unsafeAtomicAdd(&out[(size_t)(r0 + r) * UQ + col], acc[f][g2][r]);
    }
  }
}

// Fallback (ws too small): correct fp32 path, slow.
__global__ void ga_naive(const float* __restrict__ x, const float* __restrict__ w,
                         const float* __restrict__ bias, float* __restrict__ out) {
  int col = blockIdx.x * 256 + threadIdx.x;
  int row = blockIdx.y;
  int k = row >> 9, m = row & 511;
  float acc = bias[k * UQ + col];
  for (int i = 0; i < 8; ++i) {
    int j = c_sigma[i][k];
    float s = (float)c_sg[i][k];
    const float* xr = x + (size_t)(i * MBS + m) * CIN;
    const float* wc = w + (size_t)j * UQ + col;
    float a = 0.f;
    for (int c = 0; c < CIN; ++c) a = fmaf(xr[c], wc[(size_t)c * (NBL * UQ)], a);
    acc = fmaf(s, a, acc);
  }
  out[(size_t)row * UQ + col] = acc;
}

extern "C" void kernel_launch(void* const* d_in, const int* in_sizes, int n_in,
                              void* d_out, int out_size, void* d_ws, size_t ws_size,
                              hipStream_t stream) {
  const float* x    = (const float*)d_in[0];   // 4096*1024
  const float* W    = (const float*)d_in[1];   // 1024*8192
  const float* bias = (const float*)d_in[2];   // 8192
  float* out = (float*)d_out;                  // 4096*1024

  const size_t need = 32u * 1024u * 1024u;     // Xp' 8MB, Xn' 8MB, W' 16MB
  if (ws_size < need) {
    ga_naive<<<dim3(4, 4096), dim3(256), 0, stream>>>(x, W, bias, out);
    return;
  }

  uint16_t* xp = (uint16_t*)d_ws;
  uint16_t* xn = xp + 4194304;
  uint16_t* wp = xn + 4194304;

  cvt_x_kernel<<<dim3(32, 16), dim3(256), 0, stream>>>(x, (uint4*)xp, (uint4*)xn);
  cvt_w_kernel<<<dim3(128, 32), dim3(256), 0, stream>>>(W, (uint4*)wp);
  bias_fill<<<dim3(4096), dim3(256), 0, stream>>>(bias, (float4*)out);
  ga_rega<<<dim3(512), dim3(256), 0, stream>>>(xp, xn, wp, out);
}